// Round 13
// baseline (380.775 us; speedup 1.0000x reference)
//
#include <hip/hip_runtime.h>
#include <hip/hip_fp16.h>

// ---------------- problem constants ----------------
constexpr int NN = 100000;   // nodes
constexpr int NE = 1000000;  // edges
constexpr int NG = 64;       // graphs
constexpr float BN_EPS = 1e-5f;
constexpr int NTILES = NE / 32;      // 31250 wave-tiles of 32 edges
constexpr int NNTILES = NN / 32;     // 3125 node tiles
constexpr int NREC = NTILES * 2;     // 62500 boundary records

// two-level binned counting sort (512-node buckets)
constexpr int NBUK = 196;            // buckets of 512 nodes (dst >> 9)
constexpr int BINB = 256;            // binning blocks
constexpr int BCHUNK = (NE + BINB - 1) / BINB;  // 3907 edges per block
constexpr int TABN = NBUK * BINB;    // 50176 scan-table entries
constexpr int NGGRID = (NNTILES + 3) / 4;       // 782 nodegemm blocks
constexpr int NPB = 256;             // nodes per nodepass block
constexpr int NPGRID = (NN + NPB - 1) / NPB;    // 391

// ws layout (in floats)
constexpr long H1R_OFF  = 0;                       // [NN*64 f16] = 3.2M
constexpr long XNR_OFF  = 3200000;                 // [NN*64 f16] = 3.2M (adjacent to H1R)
constexpr long PART_OFF = 6400000;                 // [256*128] BN stat partials
constexpr long SC1_OFF  = PART_OFF + 32768;        // [64]
constexpr long SH1_OFF  = SC1_OFF + 64;
constexpr long SC2_OFF  = SH1_OFF + 64;
constexpr long SH2_OFF  = SC2_OFF + 64;
constexpr long PSUM_OFF = SH2_OFF + 64;            // [64*64]
constexpr long PMAX_OFF = PSUM_OFF + 4096;         // [64*64]
constexpr long CNT_OFF  = PMAX_OFF + 4096;         // [64]
constexpr long TICK_OFF = CNT_OFF + 64;            // [16] ticket counters
constexpr long TAB_OFF  = TICK_OFF + 16;           // [50176] bin scan table (int)
constexpr long SEDG_OFF = TAB_OFF + 50176;         // [NE int2] sorted (src,dst) = 2M floats
constexpr long WF1_OFF  = SEDG_OFF + 2000000;      // 12288 u16 = 6144 float slots
constexpr long WF2_OFF  = WF1_OFF + 6144;          // 12288 u16 (adjacent to WF1)
constexpr long RECD_OFF = WF2_OFF + 6144;          // [62500] record dst (int), pad->62528
constexpr long RECV_OFF = RECD_OFF + 62528;        // [62500*32 u32] = 2M; ALSO ebin staging
constexpr long P_OFF    = RECV_OFF + 2000000;      // [NN*64 f16] = 3.2M floats
constexpr long Q_OFF    = P_OFF + 3200000;         // [NN*64 f16]
constexpr int  POOLW    = 4096 + 4096 + 64 + 16;   // pools+counts+tickets words

// d_out layout (floats): z_proj [64*128] | x_node [NN*64] | x_graph [64*128]
constexpr long OUT_XNODE = 8192;
constexpr long OUT_XG    = 8192 + 6400000L;

using f16x8 = __attribute__((ext_vector_type(8))) _Float16;
using f32x16 = __attribute__((ext_vector_type(16))) float;

__device__ __forceinline__ unsigned short f2h(float f) {
    return __builtin_bit_cast(unsigned short, (_Float16)f);
}
__device__ __forceinline__ unsigned pkrtz(float a, float b) {
    return __builtin_bit_cast(unsigned, __builtin_amdgcn_cvt_pkrtz(a, b));
}
__device__ __forceinline__ unsigned pk_add_f16(unsigned a, unsigned b) {
    unsigned d;
    asm("v_pk_add_f16 %0, %1, %2" : "=v"(d) : "v"(a), "v"(b));
    return d;
}
__device__ __forceinline__ unsigned pk_max_f16(unsigned a, unsigned b) {
    unsigned d;
    asm("v_pk_max_f16 %0, %1, %2" : "=v"(d) : "v"(a), "v"(b));
    return d;
}
__device__ __forceinline__ float h2f_lo(unsigned u) {
    return (float)__builtin_bit_cast(_Float16, (unsigned short)(u & 0xffffu));
}
__device__ __forceinline__ float h2f_hi(unsigned u) {
    return (float)__builtin_bit_cast(_Float16, (unsigned short)(u >> 16));
}
__device__ __forceinline__ unsigned fenc(float f) {
    unsigned u = __float_as_uint(f);
    return (u & 0x80000000u) ? ~u : (u | 0x80000000u);
}
__device__ __forceinline__ float fdec(unsigned u) {
    return (u & 0x80000000u) ? __uint_as_float(u & 0x7fffffffu) : __uint_as_float(~u);
}
// bijective XCD-aware block swizzle (m204 variant)
__device__ __forceinline__ int xcd_swz(int bid, int nwg) {
    const int q = nwg >> 3, r = nwg & 7;
    const int x = bid & 7, i = bid >> 3;
    return (x < r ? x * (q + 1) : r * (q + 1) + (x - r) * q) + i;
}

// ---------------- nodegemm tile body (shared) ----------------
template<bool NORM>
__device__ __forceinline__ void nodegemm_tile(
    const void* __restrict__ xin, const unsigned short* wlds,
    const float* __restrict__ b1,
    const float* __restrict__ scale, const float* __restrict__ shift,
    unsigned short* __restrict__ P, unsigned short* __restrict__ Q,
    int tile, int lane)
{
    const int hi = lane >> 5, ln32 = lane & 31;
    const int node = tile * 32 + ln32;

    f32x16 cpa, cpb, cqa, cqb;
    #pragma unroll
    for (int r = 0; r < 16; ++r) {
        const int row = (r & 3) + 8 * (r >> 2) + 4 * hi;
        cpa[r] = b1[row]; cpb[r] = b1[32 + row];
        cqa[r] = 0.f;     cqb[r] = 0.f;
    }

    #pragma unroll
    for (int ks = 0; ks < 4; ++ks) {
        const int off = ks * 16 + hi * 8;
        float4 a, b;
        if constexpr (!NORM) {
            const float* xr = reinterpret_cast<const float*>(xin) + (long)node * 64;
            a = *reinterpret_cast<const float4*>(xr + off);
            b = *reinterpret_cast<const float4*>(xr + off + 4);
        } else {
            const unsigned* xr = reinterpret_cast<const unsigned*>(xin) + (long)node * 32;
            const uint4 u = *reinterpret_cast<const uint4*>(xr + ks * 8 + hi * 4);
            a.x = h2f_lo(u.x); a.y = h2f_hi(u.x); a.z = h2f_lo(u.y); a.w = h2f_hi(u.y);
            b.x = h2f_lo(u.z); b.y = h2f_hi(u.z); b.z = h2f_lo(u.w); b.w = h2f_hi(u.w);
            const float4 s0 = *reinterpret_cast<const float4*>(scale + off);
            const float4 s1 = *reinterpret_cast<const float4*>(scale + off + 4);
            const float4 h0 = *reinterpret_cast<const float4*>(shift + off);
            const float4 h1 = *reinterpret_cast<const float4*>(shift + off + 4);
            a.x = fmaf(a.x, s0.x, h0.x); a.y = fmaf(a.y, s0.y, h0.y);
            a.z = fmaf(a.z, s0.z, h0.z); a.w = fmaf(a.w, s0.w, h0.w);
            b.x = fmaf(b.x, s1.x, h1.x); b.y = fmaf(b.y, s1.y, h1.y);
            b.z = fmaf(b.z, s1.z, h1.z); b.w = fmaf(b.w, s1.w, h1.w);
        }
        uint4 uu;
        uu.x = pkrtz(a.x, a.y); uu.y = pkrtz(a.z, a.w);
        uu.z = pkrtz(b.x, b.y); uu.w = pkrtz(b.z, b.w);
        const f16x8 bfr = __builtin_bit_cast(f16x8, uu);
        const f16x8 ap0 = *reinterpret_cast<const f16x8*>(&wlds[(0 * 4 + ks) * 512 + lane * 8]);
        const f16x8 ap1 = *reinterpret_cast<const f16x8*>(&wlds[(1 * 4 + ks) * 512 + lane * 8]);
        const f16x8 aq0 = *reinterpret_cast<const f16x8*>(&wlds[4096 + (0 * 4 + ks) * 512 + lane * 8]);
        const f16x8 aq1 = *reinterpret_cast<const f16x8*>(&wlds[4096 + (1 * 4 + ks) * 512 + lane * 8]);
        cpa = __builtin_amdgcn_mfma_f32_32x32x16_f16(ap0, bfr, cpa, 0, 0, 0);
        cpb = __builtin_amdgcn_mfma_f32_32x32x16_f16(ap1, bfr, cpb, 0, 0, 0);
        cqa = __builtin_amdgcn_mfma_f32_32x32x16_f16(aq0, bfr, cqa, 0, 0, 0);
        cqb = __builtin_amdgcn_mfma_f32_32x32x16_f16(aq1, bfr, cqb, 0, 0, 0);
    }

    unsigned short* Pr = P + (long)node * 64;
    unsigned short* Qr = Q + (long)node * 64;
    #pragma unroll
    for (int t = 0; t < 2; ++t) {
        const f32x16 cp = t ? cpb : cpa;
        const f32x16 cq = t ? cqb : cqa;
        #pragma unroll
        for (int g2 = 0; g2 < 4; ++g2) {
            uint2 up, uq;
            up.x = pkrtz(cp[4 * g2 + 0], cp[4 * g2 + 1]);
            up.y = pkrtz(cp[4 * g2 + 2], cp[4 * g2 + 3]);
            uq.x = pkrtz(cq[4 * g2 + 0], cq[4 * g2 + 1]);
            uq.y = pkrtz(cq[4 * g2 + 2], cq[4 * g2 + 3]);
            const int co = t * 32 + 8 * g2 + 4 * hi;
            *reinterpret_cast<uint2*>(Pr + co) = up;
            *reinterpret_cast<uint2*>(Qr + co) = uq;
        }
    }
}

// ---------------- fused: bin_hist (blocks 0..BINB) ∥ prep_weights (rest);
// last-arriving hist block also scans the table (ticket, pre-zeroed by memset) ----
__global__ __launch_bounds__(256) void prep_hist_kernel(
    const float* __restrict__ c1w1, const float* __restrict__ c1w2,
    const float* __restrict__ c2w1, const float* __restrict__ c2w2,
    unsigned short* __restrict__ wf,
    const int* __restrict__ dst, int* __restrict__ tab, int* __restrict__ ticket)
{
    __shared__ int cnt[NBUK];
    __shared__ int part[256];
    __shared__ int flag;
    const int t = threadIdx.x;
    if (blockIdx.x < BINB) {
        const int b = blockIdx.x;
        if (t < NBUK) cnt[t] = 0;
        __syncthreads();
        const int lo = b * BCHUNK;
        const int hi = (lo + BCHUNK < NE) ? lo + BCHUNK : NE;
        for (int e = lo + t; e < hi; e += 256) atomicAdd(&cnt[dst[e] >> 9], 1);
        __syncthreads();
        if (t < NBUK) tab[t * BINB + b] = cnt[t];
        __syncthreads();
        if (t == 0) {
            __threadfence();
            flag = (atomicAdd(ticket, 1) == BINB - 1) ? 1 : 0;
        }
        __syncthreads();
        if (!flag) return;
        __threadfence();   // acquire: all blocks' tab writes visible
        // exclusive scan of tab[TABN], 256 threads, two-pass (no big reg arrays)
        constexpr int VPT = TABN / 256;  // 196
        const int base = t * VPT;
        int s = 0;
        for (int i = 0; i < VPT; ++i) s += tab[base + i];
        part[t] = s;
        __syncthreads();
        for (int off = 1; off < 256; off <<= 1) {
            const int u = (t >= off) ? part[t - off] : 0;
            __syncthreads();
            part[t] += u;
            __syncthreads();
        }
        int run = (t == 0) ? 0 : part[t - 1];
        for (int i = 0; i < VPT; ++i) {
            const int v = tab[base + i];
            tab[base + i] = run;
            run += v;
        }
        return;
    }
    // weight prep blocks
    const int gidx = (blockIdx.x - BINB) * 256 + t;   // 0..24575
    const bool second = gidx >= 12288;
    const int idx = second ? gidx - 12288 : gidx;
    const float* __restrict__ w1 = second ? c2w1 : c1w1;
    const float* __restrict__ w2 = second ? c2w2 : c1w2;
    const int sec = idx >> 12;
    const int j = idx & 4095;
    const int f = j >> 9, rem = j & 511, ln = rem >> 3, i = rem & 7;
    const int tt = f >> 2, ks = f & 3;
    const int k = ks * 16 + (ln >> 5) * 8 + i, c = tt * 32 + (ln & 31);
    float v;
    if (sec == 0)      v = w1[k * 64 + c] - w1[(64 + k) * 64 + c];
    else if (sec == 1) v = w1[(64 + k) * 64 + c];
    else               v = w2[k * 64 + c];
    wf[gidx] = f2h(v);
}

// ---------------- sort pass C: clustered scatter into bucket runs ----------------
__global__ __launch_bounds__(256) void bin_scatter_kernel(
    const int* __restrict__ src, const int* __restrict__ dst,
    const int* __restrict__ tab, int2* __restrict__ ebin)
{
    __shared__ int basec[NBUK];
    __shared__ int cur[NBUK];
    const int t = threadIdx.x, b = blockIdx.x;
    if (t < NBUK) { basec[t] = tab[t * BINB + b]; cur[t] = 0; }
    __syncthreads();
    const int lo = b * BCHUNK;
    const int hi = (lo + BCHUNK < NE) ? lo + BCHUNK : NE;
    for (int e = lo + t; e < hi; e += 256) {
        const int d = dst[e];
        const int k = d >> 9;
        const int pos = basec[k] + atomicAdd(&cur[k], 1);
        ebin[pos] = make_int2(src[e], d);
    }
}

// ---------------- fused: bucket_sort (blocks 0..NBUK) ∥ nodegemm1 (rest) ----------
__global__ __launch_bounds__(256) void bucket_ng1_kernel(
    const int2* __restrict__ ebin, const int* __restrict__ tab,
    int2* __restrict__ sedge,
    unsigned* __restrict__ h1r, unsigned* __restrict__ xnr,
    const float* __restrict__ x, const unsigned short* __restrict__ wfrag,
    const float* __restrict__ b1,
    unsigned short* __restrict__ P, unsigned short* __restrict__ Q)
{
    __shared__ int hist[512];
    __shared__ int part[256];
    __shared__ unsigned short wlds[8192];
    const int t = threadIdx.x;

    if (blockIdx.x < NBUK) {
        const int k = blockIdx.x;
        const int start = tab[k * BINB];
        const int end = (k == NBUK - 1) ? NE : tab[(k + 1) * BINB];
        hist[t * 2] = 0; hist[t * 2 + 1] = 0;
        __syncthreads();
        for (int e = start + t; e < end; e += 256) atomicAdd(&hist[ebin[e].y & 511], 1);
        __syncthreads();
        const int v0 = hist[t * 2], v1 = hist[t * 2 + 1];
        // zero rows of in-degree-0 nodes (rare); all other rows get fully overwritten
        {
            const uint4 z = make_uint4(0u, 0u, 0u, 0u);
            #pragma unroll
            for (int j = 0; j < 2; ++j) {
                const int node = k * 512 + t * 2 + j;
                const int c = j ? v1 : v0;
                if (node < NN && c == 0) {
                    uint4* r0 = reinterpret_cast<uint4*>(h1r + (long)node * 32);
                    uint4* r1 = reinterpret_cast<uint4*>(xnr + (long)node * 32);
                    #pragma unroll
                    for (int q2 = 0; q2 < 8; ++q2) { r0[q2] = z; r1[q2] = z; }
                }
            }
        }
        part[t] = v0 + v1;
        __syncthreads();
        for (int off = 1; off < 256; off <<= 1) {
            const int u = (t >= off) ? part[t - off] : 0;
            __syncthreads();
            part[t] += u;
            __syncthreads();
        }
        int run = (t == 0) ? 0 : part[t - 1];
        hist[t * 2] = run;
        hist[t * 2 + 1] = run + v0;
        __syncthreads();
        for (int e = start + t; e < end; e += 256) {
            const int2 v = ebin[e];
            const int pos = start + atomicAdd(&hist[v.y & 511], 1);
            sedge[pos] = v;
        }
        return;
    }

    // nodegemm1 blocks
    {
        const uint4* wsrc = reinterpret_cast<const uint4*>(wfrag);
        uint4* wdst = reinterpret_cast<uint4*>(wlds);
        #pragma unroll
        for (int i = 0; i < 4; ++i) wdst[t + i * 256] = wsrc[t + i * 256];
    }
    __syncthreads();
    const int wid = t >> 6, lane = t & 63;
    const int tile = (blockIdx.x - NBUK) * 4 + wid;
    if (tile >= NNTILES) return;
    nodegemm_tile<false>(x, wlds, b1, nullptr, nullptr, P, Q, tile, lane);
}

// ---------------- standalone node GEMM (conv2) ----------------
__global__ __launch_bounds__(256) void nodegemm_kernel(
    const void* __restrict__ xin,
    const unsigned short* __restrict__ wfrag,
    const float* __restrict__ b1,
    const float* __restrict__ scale, const float* __restrict__ shift,
    unsigned short* __restrict__ P, unsigned short* __restrict__ Q)
{
    __shared__ unsigned short wlds[8192];
    {
        const uint4* wsrc = reinterpret_cast<const uint4*>(wfrag);
        uint4* wdst = reinterpret_cast<uint4*>(wlds);
        #pragma unroll
        for (int i = 0; i < 4; ++i) wdst[threadIdx.x + i * 256] = wsrc[threadIdx.x + i * 256];
    }
    __syncthreads();
    const int wid = threadIdx.x >> 6, lane = threadIdx.x & 63;
    const int tile = blockIdx.x * 4 + wid;
    if (tile >= NNTILES) return;
    nodegemm_tile<true>(xin, wlds, b1, scale, shift, P, Q, tile, lane);
}

// ---------------- EdgeConv layer-2: wave = 32 sorted edges ----------------
__global__ __launch_bounds__(256) void edgeconv_kernel(
    const unsigned short* __restrict__ P, const unsigned short* __restrict__ Q,
    const int2* __restrict__ sedge,
    const unsigned short* __restrict__ w2frag,
    const float* __restrict__ b2,
    unsigned* __restrict__ out,              // [NN][32] f16-pair dwords
    int* __restrict__ recd, unsigned* __restrict__ recv)  // recv [NREC][32]
{
    __shared__ unsigned short wlds[4096];
    {
        const uint4* wsrc = reinterpret_cast<const uint4*>(w2frag);
        uint4* wdst = reinterpret_cast<uint4*>(wlds);
        #pragma unroll
        for (int i = 0; i < 2; ++i) wdst[threadIdx.x + i * 256] = wsrc[threadIdx.x + i * 256];
    }
    __syncthreads();

    const int wid  = threadIdx.x >> 6;
    const int lane = threadIdx.x & 63;
    const int hi   = lane >> 5;
    const int ln32 = lane & 31;
    const int tile = xcd_swz(blockIdx.x, gridDim.x) * 4 + wid;  // XCD-chunked for P L2 locality
    if (tile >= NTILES) return;

    const int2 sd = sedge[tile * 32 + ln32];
    const int s = sd.x, d = sd.y;
    const unsigned short* __restrict__ Pr = P + (long)d * 64;
    const unsigned short* __restrict__ Qr = Q + (long)s * 64;

    f32x16 c2a, c2b;
    #pragma unroll
    for (int r = 0; r < 16; ++r) {
        const int row = (r & 3) + 8 * (r >> 2) + 4 * hi;
        c2a[r] = b2[row];
        c2b[r] = b2[32 + row];
    }

    #pragma unroll
    for (int ks = 0; ks < 4; ++ks) {
        const int co = ks * 16 + hi * 8;
        const uint4 pu = *reinterpret_cast<const uint4*>(Pr + co);
        const uint4 qu = *reinterpret_cast<const uint4*>(Qr + co);
        uint4 hh;   // relu(P+Q) in packed f16
        hh.x = pk_max_f16(pk_add_f16(pu.x, qu.x), 0u);
        hh.y = pk_max_f16(pk_add_f16(pu.y, qu.y), 0u);
        hh.z = pk_max_f16(pk_add_f16(pu.z, qu.z), 0u);
        hh.w = pk_max_f16(pk_add_f16(pu.w, qu.w), 0u);
        const f16x8 bfr = __builtin_bit_cast(f16x8, hh);
        const f16x8 a0 = *reinterpret_cast<const f16x8*>(&wlds[(0 * 4 + ks) * 512 + lane * 8]);
        const f16x8 a1 = *reinterpret_cast<const f16x8*>(&wlds[(1 * 4 + ks) * 512 + lane * 8]);
        c2a = __builtin_amdgcn_mfma_f32_32x32x16_f16(a0, bfr, c2a, 0, 0, 0);
        c2b = __builtin_amdgcn_mfma_f32_32x32x16_f16(a1, bfr, c2b, 0, 0, 0);
    }

    // relu + pack to 16 f16-pair dwords
    unsigned pkc[16];
    #pragma unroll
    for (int q = 0; q < 8; ++q) {
        pkc[q]     = pk_max_f16(pkrtz(c2a[2 * q], c2a[2 * q + 1]), 0u);
        pkc[8 + q] = pk_max_f16(pkrtz(c2b[2 * q], c2b[2 * q + 1]), 0u);
    }

    // segmented max over edges within each 32-lane half (keys = d, sorted)
    #pragma unroll
    for (int st = 1; st < 16; st <<= 1) {
        const int dn = __shfl_down(d, st, 32);
        const bool take = (ln32 + st < 32) && (dn == d);
        #pragma unroll
        for (int i = 0; i < 16; ++i) {
            const unsigned o = __shfl_down(pkc[i], st, 32);
            const unsigned m = pk_max_f16(pkc[i], o);
            pkc[i] = take ? m : pkc[i];
        }
    }
    // stage 16 only when some segment spans >16 lanes (~8% of tiles)
    {
        const int dn = __shfl_down(d, 16, 32);
        const bool take = (ln32 + 16 < 32) && (dn == d);
        if (__ballot(take) != 0ull) {
            #pragma unroll
            for (int i = 0; i < 16; ++i) {
                const unsigned o = __shfl_down(pkc[i], 16, 32);
                const unsigned m = pk_max_f16(pkc[i], o);
                pkc[i] = take ? m : pkc[i];
            }
        }
    }
    const int dprev = __shfl_up(d, 1, 32);
    const bool leader = (ln32 == 0) || (d != dprev);
    const unsigned lm = (unsigned)(__ballot(leader) & 0xffffffffull);
    const int L31 = 31 - __builtin_clz(lm);

    if (leader) {
        if (ln32 != 0 && ln32 != L31) {
            unsigned* row = out + (long)d * 32;
            #pragma unroll
            for (int g2 = 0; g2 < 4; ++g2) {
                *reinterpret_cast<uint2*>(row + 4 * g2 + 2 * hi) =
                    make_uint2(pkc[2 * g2], pkc[2 * g2 + 1]);
                *reinterpret_cast<uint2*>(row + 16 + 4 * g2 + 2 * hi) =
                    make_uint2(pkc[8 + 2 * g2], pkc[8 + 2 * g2 + 1]);
            }
        }
        if (ln32 == 0) {
            unsigned* row = recv + (long)(tile * 2) * 32;
            #pragma unroll
            for (int g2 = 0; g2 < 4; ++g2) {
                *reinterpret_cast<uint2*>(row + 4 * g2 + 2 * hi) =
                    make_uint2(pkc[2 * g2], pkc[2 * g2 + 1]);
                *reinterpret_cast<uint2*>(row + 16 + 4 * g2 + 2 * hi) =
                    make_uint2(pkc[8 + 2 * g2], pkc[8 + 2 * g2 + 1]);
            }
            if (hi == 0) recd[tile * 2] = d;
        }
        if (ln32 == L31) {
            unsigned* row = recv + (long)(tile * 2 + 1) * 32;
            #pragma unroll
            for (int g2 = 0; g2 < 4; ++g2) {
                *reinterpret_cast<uint2*>(row + 4 * g2 + 2 * hi) =
                    make_uint2(pkc[2 * g2], pkc[2 * g2 + 1]);
                *reinterpret_cast<uint2*>(row + 16 + 4 * g2 + 2 * hi) =
                    make_uint2(pkc[8 + 2 * g2], pkc[8 + 2 * g2 + 1]);
            }
            if (hi == 0) recd[tile * 2 + 1] = d;
        }
    }
}

// ---------------- fixup: combine boundary records, 2 records per wave -------------
__global__ __launch_bounds__(256) void fixup_kernel(
    const int* __restrict__ recd, const unsigned* __restrict__ recv,
    unsigned* __restrict__ out)
{
    const int wid = threadIdx.x >> 6;
    const int half = (threadIdx.x >> 5) & 1;
    const int c2 = threadIdx.x & 31;
    const int r = blockIdx.x * 8 + wid * 2 + half;
    if (r >= NREC) return;
    const int d = recd[r];
    int lo = r, hi = r;
    while (lo > 0 && recd[lo - 1] == d) --lo;
    while (hi + 1 < NREC && recd[hi + 1] == d) ++hi;
    unsigned m = 0u;   // relu outputs >= 0 -> packed {+0,+0} identity
    for (int rr = lo; rr <= hi; ++rr) m = pk_max_f16(m, recv[(long)rr * 32 + c2]);
    out[(long)d * 32 + c2] = m;
}

// ---------------- BN stats over f16 rows + fused finalize (ticket) ----------------
__global__ __launch_bounds__(256) void stats_kernel(
    const unsigned* __restrict__ h, float* __restrict__ partial,
    const float* __restrict__ g, const float* __restrict__ b,
    float* __restrict__ scale, float* __restrict__ shift, int* __restrict__ ticket)
{
    __shared__ float red[4][256];
    __shared__ float red2[2][256];
    __shared__ int flag;
    const int tid = threadIdx.x;
    const int c2 = tid & 31, r = tid >> 5;   // 8 rows in flight
    float s0 = 0.f, ss0 = 0.f, s1 = 0.f, ss1 = 0.f;
    for (int v = blockIdx.x * 8 + r; v < NN; v += 256 * 8) {
        const unsigned u = h[(long)v * 32 + c2];
        const float a = h2f_lo(u), bb = h2f_hi(u);
        s0 += a; ss0 += a * a; s1 += bb; ss1 += bb * bb;
    }
    red[0][tid] = s0; red[1][tid] = ss0; red[2][tid] = s1; red[3][tid] = ss1;
    __syncthreads();
    if (r == 0) {
        float S0 = 0.f, SS0 = 0.f, S1 = 0.f, SS1 = 0.f;
        #pragma unroll
        for (int q = 0; q < 8; ++q) {
            S0 += red[0][c2 + q * 32]; SS0 += red[1][c2 + q * 32];
            S1 += red[2][c2 + q * 32]; SS1 += red[3][c2 + q * 32];
        }
        partial[blockIdx.x * 128 + 2 * c2]     = S0;
        partial[blockIdx.x * 128 + 2 * c2 + 1] = S1;
        partial[blockIdx.x * 128 + 64 + 2 * c2]     = SS0;
        partial[blockIdx.x * 128 + 64 + 2 * c2 + 1] = SS1;
    }
    __syncthreads();
    if (tid == 0) {
        __threadfence();
        flag = (atomicAdd(ticket, 1) == 255) ? 1 : 0;
    }
    __syncthreads();
    if (!flag) return;
    __threadfence();   // acquire: all blocks' partials visible
    const int c = tid & 63, q = tid >> 6;
    float S = 0.f, SS = 0.f;
    for (int bb2 = q * 64; bb2 < q * 64 + 64; ++bb2) {
        S += partial[bb2 * 128 + c];
        SS += partial[bb2 * 128 + 64 + c];
    }
    red2[0][tid] = S; red2[1][tid] = SS;
    __syncthreads();
    if (q == 0) {
        #pragma unroll
        for (int p = 1; p < 4; ++p) { S += red2[0][c + p * 64]; SS += red2[1][c + p * 64]; }
        const float invN = 1.0f / (float)NN;
        const float mu = S * invN;
        const float var = SS * invN - mu * mu;
        const float sc = g[c] * rsqrtf(var + BN_EPS);
        scale[c] = sc;
        shift[c] = b[c] - mu * sc;
    }
}

// ---------------- node pass: BN2 normalize + pooling; last block runs projector ----
__global__ __launch_bounds__(256) void nodepass_final_kernel(
    const unsigned* __restrict__ xnr, float* __restrict__ xn,
    const int* __restrict__ batch,
    const float* __restrict__ scale, const float* __restrict__ shift,
    float* __restrict__ poolsum, unsigned* __restrict__ poolmax,
    int* __restrict__ counts, int* __restrict__ ticket,
    const float* __restrict__ p_w1, const float* __restrict__ p_b1,
    const float* __restrict__ p_bng, const float* __restrict__ p_bnb,
    const float* __restrict__ p_w2, const float* __restrict__ p_b2,
    float* __restrict__ out)
{
    __shared__ float xg[64][128];
    __shared__ float znl[64 * 129];
    __shared__ float red[2][256];
    __shared__ float scsh[2][128];
    __shared__ int flag;

    // ---- nodepass part ----
    {
        const int base = blockIdx.x * NPB;
        const int r = threadIdx.x >> 5, c2 = threadIdx.x & 31;
        const float sc0 = scale[2 * c2], sc1 = scale[2 * c2 + 1];
        const float sh0 = shift[2 * c2], sh1 = shift[2 * c2 + 1];
        int curg = -1; float rs0 = 0.f, rs1 = 0.f, rm0 = -INFINITY, rm1 = -INFINITY; int rc = 0;
        const int vend = (base + NPB < NN) ? base + NPB : NN;
        for (int v = base + r; v < vend; v += 8) {
            const unsigned u = xnr[(long)v * 32 + c2];
            const float v0 = fmaf(h2f_lo(u), sc0, sh0);
            const float v1 = fmaf(h2f_hi(u), sc1, sh1);
            *reinterpret_cast<float2*>(xn + (long)v * 64 + 2 * c2) = make_float2(v0, v1);
            const int g = batch[v];
            if (g != curg) {
                if (curg >= 0) {
                    atomicAdd(poolsum + curg * 64 + 2 * c2, rs0);
                    atomicAdd(poolsum + curg * 64 + 2 * c2 + 1, rs1);
                    atomicMax(poolmax + curg * 64 + 2 * c2, fenc(rm0));
                    atomicMax(poolmax + curg * 64 + 2 * c2 + 1, fenc(rm1));
                    if (c2 == 0) atomicAdd(counts + curg, rc);
                }
                curg = g; rs0 = rs1 = 0.f; rm0 = rm1 = -INFINITY; rc = 0;
            }
            rs0 += v0; rs1 += v1; rm0 = fmaxf(rm0, v0); rm1 = fmaxf(rm1, v1); ++rc;
        }
        if (curg >= 0) {
            atomicAdd(poolsum + curg * 64 + 2 * c2, rs0);
            atomicAdd(poolsum + curg * 64 + 2 * c2 + 1, rs1);
            atomicMax(poolmax + curg * 64 + 2 * c2, fenc(rm0));
            atomicMax(poolmax + curg * 64 + 2 * c2 + 1, fenc(rm1));
            if (c2 == 0) atomicAdd(counts + curg, rc);
        }
    }
    __syncthreads();
    if (threadIdx.x == 0) {
        __threadfence();
        flag = (atomicAdd(ticket, 1) == NPGRID - 1) ? 1 : 0;
    }
    __syncthreads();
    if (!flag) return;
    __threadfence();   // acquire: all blocks' pool atomics visible

    // ---- projector part (256 threads; 2 graph-groups of 32) ----
    const int tid = threadIdx.x;
    #pragma unroll
    for (int i = 0; i < 32; ++i) {
        const int e2 = tid + i * 256;
        const int g = e2 >> 7, col = e2 & 127;
        float val;
        if (col < 64) {
            const float cnt = fmaxf((float)counts[g], 1.f);
            val = poolsum[g * 64 + col] / cnt;
        } else {
            const unsigned u = poolmax[g * 64 + col - 64];
            val = (u == 0u) ? 0.f : fdec(u);
        }
        xg[g][col] = val;
        out[OUT_XG + e2] = val;
    }
    __syncthreads();

    const int gg = tid >> 7, t = tid & 127;   // gg in {0,1}, 32 graphs each
    float z[32];
    #pragma unroll
    for (int gi = 0; gi < 32; ++gi) z[gi] = p_b1[t];
    for (int j = 0; j < 128; ++j) {
        const float wv = p_w1[j * 128 + t];
        #pragma unroll
        for (int gi = 0; gi < 32; ++gi) z[gi] = fmaf(xg[gg * 32 + gi][j], wv, z[gi]);
    }

    float s = 0.f, ss = 0.f;
    #pragma unroll
    for (int gi = 0; gi < 32; ++gi) { s += z[gi]; ss += z[gi] * z[gi]; }
    red[0][tid] = s; red[1][tid] = ss;
    __syncthreads();
    if (gg == 0) {
        const float S = red[0][t] + red[0][t + 128];
        const float SS = red[1][t] + red[1][t + 128];
        const float mu = S / 64.f;
        const float var = SS / 64.f - mu * mu;
        const float sc = p_bng[t] * rsqrtf(var + BN_EPS);
        scsh[0][t] = sc;
        scsh[1][t] = p_bnb[t] - mu * sc;
    }
    __syncthreads();
    const float sc = scsh[0][t], sh = scsh[1][t];
    #pragma unroll
    for (int gi = 0; gi < 32; ++gi) {
        const float zn = fmaxf(fmaf(z[gi], sc, sh), 0.f);
        znl[(gg * 32 + gi) * 129 + t] = zn;
    }
    __syncthreads();

    float zp[32];
    #pragma unroll
    for (int gi = 0; gi < 32; ++gi) zp[gi] = p_b2[t];
    for (int c = 0; c < 128; ++c) {
        const float wv = p_w2[c * 128 + t];
        #pragma unroll
        for (int gi = 0; gi < 32; ++gi) zp[gi] = fmaf(znl[(gg * 32 + gi) * 129 + c], wv, zp[gi]);
    }
    #pragma unroll
    for (int gi = 0; gi < 32; ++gi) out[(gg * 32 + gi) * 128 + t] = zp[gi];
}

// ---------------- launch ----------------
extern "C" void kernel_launch(void* const* d_in, const int* in_sizes, int n_in,
                              void* d_out, int out_size, void* d_ws, size_t ws_size,
                              hipStream_t stream)
{
    const float* x     = (const float*)d_in[0];
    const int*   eidx  = (const int*)d_in[1];
    const int*   batch = (const int*)d_in[2];
    const float* c1w1  = (const float*)d_in[3];
    const float* c1b1  = (const float*)d_in[4];
    const float* c1w2  = (const float*)d_in[5];
    const float* c1b2  = (const float*)d_in[6];
    const float* bn1g  = (const float*)d_in[7];
    const float* bn1b  = (const float*)d_in[8];
    const float* c2w1  = (const float*)d_in[9];
    const float* c2b1  = (const float*)d_in[10];
    const float* c2w2  = (const float*)d_in[11];
    const float* c2b2  = (const float*)d_in[12];
    const float* bn2g  = (const float*)d_in[13];
    const float* bn2b  = (const float*)d_in[14];
    const float* pw1   = (const float*)d_in[15];
    const float* pb1   = (const float*)d_in[16];
    const float* pbng  = (const float*)d_in[17];
    const float* pbnb  = (const float*)d_in[18];
    const float* pw2   = (const float*)d_in[19];
    const float* pb2   = (const float*)d_in[20];

    const int* src = eidx;
    const int* dst = eidx + NE;

    float* ws  = (float*)d_ws;
    float* o   = (float*)d_out;
    unsigned* h1r = (unsigned*)(ws + H1R_OFF);   // f16 rows as dwords
    unsigned* xnr = (unsigned*)(ws + XNR_OFF);
    float* xnode = o + OUT_XNODE;
    int* tick  = (int*)(ws + TICK_OFF);
    int* tab   = (int*)(ws + TAB_OFF);
    int2* ebin  = (int2*)(ws + RECV_OFF);   // staging in RECV region (disjoint lifetime)
    int2* sedge = (int2*)(ws + SEDG_OFF);
    unsigned short* wf1 = (unsigned short*)(ws + WF1_OFF);
    unsigned short* wf2 = (unsigned short*)(ws + WF2_OFF);
    int* recd  = (int*)(ws + RECD_OFF);
    unsigned* recv = (unsigned*)(ws + RECV_OFF);
    unsigned short* Pb = (unsigned short*)(ws + P_OFF);
    unsigned short* Qb = (unsigned short*)(ws + Q_OFF);

    const int convGrid = (NTILES + 3) / 4;
    const int fixGrid  = (NREC + 7) / 8;

    // zero pools + counts + tickets (33 KB) — tickets must be 0 before prep_hist
    hipMemsetAsync(ws + PSUM_OFF, 0, POOLW * 4, stream);

    // weight prep ∥ bucket histogram; last hist block scans the table (ticket 0)
    prep_hist_kernel<<<BINB + 96, 256, 0, stream>>>(
        c1w1, c1w2, c2w1, c2w2, wf1, dst, tab, tick + 0);
    // clustered scatter into bucket runs
    bin_scatter_kernel<<<BINB, 256, 0, stream>>>(src, dst, tab, ebin);
    // per-bucket counting sort (+ zero empty rows) ∥ nodegemm1
    bucket_ng1_kernel<<<NBUK + NGGRID, 256, 0, stream>>>(
        ebin, tab, sedge, h1r, xnr, x, wf1, c1b1, Pb, Qb);

    // conv1 edge pass -> h1r (f16)
    edgeconv_kernel<<<convGrid, 256, 0, stream>>>(
        Pb, Qb, sedge, wf1 + 8192, c1b2, h1r, recd, recv);
    fixup_kernel<<<fixGrid, 256, 0, stream>>>(recd, recv, h1r);
    // BN1 stats + fused finalize (ticket 1)
    stats_kernel<<<256, 256, 0, stream>>>(h1r, ws + PART_OFF, bn1g, bn1b,
                                          ws + SC1_OFF, ws + SH1_OFF, tick + 1);
    // conv2: node GEMM on normalized h1r, edge pass -> xnr
    nodegemm_kernel<<<NGGRID, 256, 0, stream>>>(
        h1r, wf2, c2b1, ws + SC1_OFF, ws + SH1_OFF, Pb, Qb);
    edgeconv_kernel<<<convGrid, 256, 0, stream>>>(
        Pb, Qb, sedge, wf2 + 8192, c2b2, xnr, recd, recv);
    fixup_kernel<<<fixGrid, 256, 0, stream>>>(recd, recv, xnr);
    // BN2 stats + fused finalize (ticket 2)
    stats_kernel<<<256, 256, 0, stream>>>(xnr, ws + PART_OFF, bn2g, bn2b,
                                          ws + SC2_OFF, ws + SH2_OFF, tick + 2);
    // normalize xnr -> x_node + pooling; last block runs projector (ticket 3)
    nodepass_final_kernel<<<NPGRID, 256, 0, stream>>>(
        xnr, xnode, batch, ws + SC2_OFF, ws + SH2_OFF,
        ws + PSUM_OFF, (unsigned*)(ws + PMAX_OFF), (int*)(ws + CNT_OFF), tick + 3,
        pw1, pb1, pbng, pbnb, pw2, pb2, o);
}

// Round 14
// 334.387 us; speedup vs baseline: 1.1387x; 1.1387x over previous
//
#include <hip/hip_runtime.h>
#include <hip/hip_fp16.h>

// ---------------- problem constants ----------------
constexpr int NN = 100000;   // nodes
constexpr int NE = 1000000;  // edges
constexpr int NG = 64;       // graphs
constexpr float BN_EPS = 1e-5f;
constexpr int NTILES = NE / 32;      // 31250 wave-tiles of 32 edges
constexpr int NNTILES = NN / 32;     // 3125 node tiles
constexpr int NREC = NTILES * 2;     // 62500 boundary records

// two-level binned counting sort (512-node buckets)
constexpr int NBUK = 196;            // buckets of 512 nodes (dst >> 9)
constexpr int BINB = 256;            // binning blocks
constexpr int BCHUNK = (NE + BINB - 1) / BINB;  // 3907 edges per block
constexpr int TABN = NBUK * BINB;    // 50176 scan-table entries
constexpr int NGGRID = (NNTILES + 3) / 4;       // 782 nodegemm blocks

// ws layout (in floats)
constexpr long H1R_OFF  = 0;                       // [NN*64 f16] = 3.2M
constexpr long XNR_OFF  = 3200000;                 // [NN*64 f16] = 3.2M (adjacent to H1R)
constexpr long PART_OFF = 6400000;                 // [256*128] BN stat partials
constexpr long SC1_OFF  = PART_OFF + 32768;        // [64]
constexpr long SH1_OFF  = SC1_OFF + 64;
constexpr long SC2_OFF  = SH1_OFF + 64;
constexpr long SH2_OFF  = SC2_OFF + 64;
constexpr long PSUM_OFF = SH2_OFF + 64;            // [64*64]
constexpr long PMAX_OFF = PSUM_OFF + 4096;         // [64*64]
constexpr long CNT_OFF  = PMAX_OFF + 4096;         // [64]
constexpr long TICK_OFF = CNT_OFF + 64;            // [16] ticket counters
constexpr long TAB_OFF  = TICK_OFF + 16;           // [50176] bin scan table (int)
constexpr long SEDG_OFF = TAB_OFF + 50176;         // [NE int2] sorted (src,dst) = 2M floats
constexpr long WF1_OFF  = SEDG_OFF + 2000000;      // 12288 u16 = 6144 float slots
constexpr long WF2_OFF  = WF1_OFF + 6144;          // 12288 u16 (adjacent to WF1)
constexpr long RECD_OFF = WF2_OFF + 6144;          // [62500] record dst (int), pad->62528
constexpr long RECV_OFF = RECD_OFF + 62528;        // [62500*32 u32] = 2M; ALSO ebin staging
constexpr long P_OFF    = RECV_OFF + 2000000;      // [NN*64 f16] = 3.2M floats
constexpr long Q_OFF    = P_OFF + 3200000;         // [NN*64 f16]
constexpr int  POOLW    = 4096 + 4096 + 64 + 16;   // pools+counts+tickets words

// d_out layout (floats): z_proj [64*128] | x_node [NN*64] | x_graph [64*128]
constexpr long OUT_XNODE = 8192;
constexpr long OUT_XG    = 8192 + 6400000L;

using f16x8 = __attribute__((ext_vector_type(8))) _Float16;
using f32x16 = __attribute__((ext_vector_type(16))) float;

__device__ __forceinline__ unsigned short f2h(float f) {
    return __builtin_bit_cast(unsigned short, (_Float16)f);
}
__device__ __forceinline__ unsigned pkrtz(float a, float b) {
    return __builtin_bit_cast(unsigned, __builtin_amdgcn_cvt_pkrtz(a, b));
}
__device__ __forceinline__ unsigned pk_add_f16(unsigned a, unsigned b) {
    unsigned d;
    asm("v_pk_add_f16 %0, %1, %2" : "=v"(d) : "v"(a), "v"(b));
    return d;
}
__device__ __forceinline__ unsigned pk_max_f16(unsigned a, unsigned b) {
    unsigned d;
    asm("v_pk_max_f16 %0, %1, %2" : "=v"(d) : "v"(a), "v"(b));
    return d;
}
__device__ __forceinline__ float h2f_lo(unsigned u) {
    return (float)__builtin_bit_cast(_Float16, (unsigned short)(u & 0xffffu));
}
__device__ __forceinline__ float h2f_hi(unsigned u) {
    return (float)__builtin_bit_cast(_Float16, (unsigned short)(u >> 16));
}
__device__ __forceinline__ unsigned fenc(float f) {
    unsigned u = __float_as_uint(f);
    return (u & 0x80000000u) ? ~u : (u | 0x80000000u);
}
__device__ __forceinline__ float fdec(unsigned u) {
    return (u & 0x80000000u) ? __uint_as_float(u & 0x7fffffffu) : __uint_as_float(~u);
}
// bijective XCD-aware block swizzle (m204 variant)
__device__ __forceinline__ int xcd_swz(int bid, int nwg) {
    const int q = nwg >> 3, r = nwg & 7;
    const int x = bid & 7, i = bid >> 3;
    return (x < r ? x * (q + 1) : r * (q + 1) + (x - r) * q) + i;
}

// ---------------- nodegemm tile body (shared) ----------------
template<bool NORM>
__device__ __forceinline__ void nodegemm_tile(
    const void* __restrict__ xin, const unsigned short* wlds,
    const float* __restrict__ b1,
    const float* __restrict__ scale, const float* __restrict__ shift,
    unsigned short* __restrict__ P, unsigned short* __restrict__ Q,
    int tile, int lane)
{
    const int hi = lane >> 5, ln32 = lane & 31;
    const int node = tile * 32 + ln32;

    f32x16 cpa, cpb, cqa, cqb;
    #pragma unroll
    for (int r = 0; r < 16; ++r) {
        const int row = (r & 3) + 8 * (r >> 2) + 4 * hi;
        cpa[r] = b1[row]; cpb[r] = b1[32 + row];
        cqa[r] = 0.f;     cqb[r] = 0.f;
    }

    #pragma unroll
    for (int ks = 0; ks < 4; ++ks) {
        const int off = ks * 16 + hi * 8;
        float4 a, b;
        if constexpr (!NORM) {
            const float* xr = reinterpret_cast<const float*>(xin) + (long)node * 64;
            a = *reinterpret_cast<const float4*>(xr + off);
            b = *reinterpret_cast<const float4*>(xr + off + 4);
        } else {
            const unsigned* xr = reinterpret_cast<const unsigned*>(xin) + (long)node * 32;
            const uint4 u = *reinterpret_cast<const uint4*>(xr + ks * 8 + hi * 4);
            a.x = h2f_lo(u.x); a.y = h2f_hi(u.x); a.z = h2f_lo(u.y); a.w = h2f_hi(u.y);
            b.x = h2f_lo(u.z); b.y = h2f_hi(u.z); b.z = h2f_lo(u.w); b.w = h2f_hi(u.w);
            const float4 s0 = *reinterpret_cast<const float4*>(scale + off);
            const float4 s1 = *reinterpret_cast<const float4*>(scale + off + 4);
            const float4 h0 = *reinterpret_cast<const float4*>(shift + off);
            const float4 h1 = *reinterpret_cast<const float4*>(shift + off + 4);
            a.x = fmaf(a.x, s0.x, h0.x); a.y = fmaf(a.y, s0.y, h0.y);
            a.z = fmaf(a.z, s0.z, h0.z); a.w = fmaf(a.w, s0.w, h0.w);
            b.x = fmaf(b.x, s1.x, h1.x); b.y = fmaf(b.y, s1.y, h1.y);
            b.z = fmaf(b.z, s1.z, h1.z); b.w = fmaf(b.w, s1.w, h1.w);
        }
        uint4 uu;
        uu.x = pkrtz(a.x, a.y); uu.y = pkrtz(a.z, a.w);
        uu.z = pkrtz(b.x, b.y); uu.w = pkrtz(b.z, b.w);
        const f16x8 bfr = __builtin_bit_cast(f16x8, uu);
        const f16x8 ap0 = *reinterpret_cast<const f16x8*>(&wlds[(0 * 4 + ks) * 512 + lane * 8]);
        const f16x8 ap1 = *reinterpret_cast<const f16x8*>(&wlds[(1 * 4 + ks) * 512 + lane * 8]);
        const f16x8 aq0 = *reinterpret_cast<const f16x8*>(&wlds[4096 + (0 * 4 + ks) * 512 + lane * 8]);
        const f16x8 aq1 = *reinterpret_cast<const f16x8*>(&wlds[4096 + (1 * 4 + ks) * 512 + lane * 8]);
        cpa = __builtin_amdgcn_mfma_f32_32x32x16_f16(ap0, bfr, cpa, 0, 0, 0);
        cpb = __builtin_amdgcn_mfma_f32_32x32x16_f16(ap1, bfr, cpb, 0, 0, 0);
        cqa = __builtin_amdgcn_mfma_f32_32x32x16_f16(aq0, bfr, cqa, 0, 0, 0);
        cqb = __builtin_amdgcn_mfma_f32_32x32x16_f16(aq1, bfr, cqb, 0, 0, 0);
    }

    unsigned short* Pr = P + (long)node * 64;
    unsigned short* Qr = Q + (long)node * 64;
    #pragma unroll
    for (int t = 0; t < 2; ++t) {
        const f32x16 cp = t ? cpb : cpa;
        const f32x16 cq = t ? cqb : cqa;
        #pragma unroll
        for (int g2 = 0; g2 < 4; ++g2) {
            uint2 up, uq;
            up.x = pkrtz(cp[4 * g2 + 0], cp[4 * g2 + 1]);
            up.y = pkrtz(cp[4 * g2 + 2], cp[4 * g2 + 3]);
            uq.x = pkrtz(cq[4 * g2 + 0], cq[4 * g2 + 1]);
            uq.y = pkrtz(cq[4 * g2 + 2], cq[4 * g2 + 3]);
            const int co = t * 32 + 8 * g2 + 4 * hi;
            *reinterpret_cast<uint2*>(Pr + co) = up;
            *reinterpret_cast<uint2*>(Qr + co) = uq;
        }
    }
}

// ---------------- fused: bin_hist (blocks 0..BINB) ∥ prep_weights + pool zero ------
__global__ __launch_bounds__(256) void prep_hist_kernel(
    const float* __restrict__ c1w1, const float* __restrict__ c1w2,
    const float* __restrict__ c2w1, const float* __restrict__ c2w2,
    unsigned short* __restrict__ wf, float* __restrict__ pools,
    const int* __restrict__ dst, int* __restrict__ tab)
{
    __shared__ int cnt[NBUK];
    const int t = threadIdx.x;
    if (blockIdx.x < BINB) {
        const int b = blockIdx.x;
        if (t < NBUK) cnt[t] = 0;
        __syncthreads();
        const int lo = b * BCHUNK;
        const int hi = (lo + BCHUNK < NE) ? lo + BCHUNK : NE;
        for (int e = lo + t; e < hi; e += 256) atomicAdd(&cnt[dst[e] >> 9], 1);
        __syncthreads();
        if (t < NBUK) tab[t * BINB + b] = cnt[t];
        return;
    }
    const int gidx = (blockIdx.x - BINB) * 256 + t;
    if (gidx >= 24576) {
        const int z = gidx - 24576;
        if (z < POOLW) pools[z] = 0.f;
        return;
    }
    const bool second = gidx >= 12288;
    const int idx = second ? gidx - 12288 : gidx;
    const float* __restrict__ w1 = second ? c2w1 : c1w1;
    const float* __restrict__ w2 = second ? c2w2 : c1w2;
    const int sec = idx >> 12;
    const int j = idx & 4095;
    const int f = j >> 9, rem = j & 511, ln = rem >> 3, i = rem & 7;
    const int tt = f >> 2, ks = f & 3;
    const int k = ks * 16 + (ln >> 5) * 8 + i, c = tt * 32 + (ln & 31);
    float v;
    if (sec == 0)      v = w1[k * 64 + c] - w1[(64 + k) * 64 + c];
    else if (sec == 1) v = w1[(64 + k) * 64 + c];
    else               v = w2[k * 64 + c];
    wf[gidx] = f2h(v);
}

// ---------------- sort pass B: exclusive scan of the table (1024 threads) ---------
__global__ __launch_bounds__(1024) void scan_tab_kernel(int* __restrict__ tab)
{
    __shared__ int part[1024];
    const int t = threadIdx.x;
    constexpr int VPT = 49;  // 1024*49 = 50176 = TABN
    int vals[VPT];
    const int base = t * VPT;
    int s = 0;
    #pragma unroll
    for (int i = 0; i < VPT; ++i) {
        const int idx = base + i;
        const int v = (idx < TABN) ? tab[idx] : 0;
        vals[i] = v; s += v;
    }
    part[t] = s;
    __syncthreads();
    for (int off = 1; off < 1024; off <<= 1) {
        const int u = (t >= off) ? part[t - off] : 0;
        __syncthreads();
        part[t] += u;
        __syncthreads();
    }
    int run = (t == 0) ? 0 : part[t - 1];
    #pragma unroll
    for (int i = 0; i < VPT; ++i) {
        const int idx = base + i;
        if (idx < TABN) { const int v = vals[i]; tab[idx] = run; run += v; }
    }
}

// ---------------- sort pass C: clustered scatter into bucket runs ----------------
__global__ __launch_bounds__(256) void bin_scatter_kernel(
    const int* __restrict__ src, const int* __restrict__ dst,
    const int* __restrict__ tab, int2* __restrict__ ebin)
{
    __shared__ int basec[NBUK];
    __shared__ int cur[NBUK];
    const int t = threadIdx.x, b = blockIdx.x;
    if (t < NBUK) { basec[t] = tab[t * BINB + b]; cur[t] = 0; }
    __syncthreads();
    const int lo = b * BCHUNK;
    const int hi = (lo + BCHUNK < NE) ? lo + BCHUNK : NE;
    for (int e = lo + t; e < hi; e += 256) {
        const int d = dst[e];
        const int k = d >> 9;
        const int pos = basec[k] + atomicAdd(&cur[k], 1);
        ebin[pos] = make_int2(src[e], d);
    }
}

// ---------------- fused: bucket_sort (blocks 0..NBUK) ∥ nodegemm1 (rest) ----------
__global__ __launch_bounds__(256) void bucket_ng1_kernel(
    const int2* __restrict__ ebin, const int* __restrict__ tab,
    int2* __restrict__ sedge,
    unsigned* __restrict__ h1r, unsigned* __restrict__ xnr,
    const float* __restrict__ x, const unsigned short* __restrict__ wfrag,
    const float* __restrict__ b1,
    unsigned short* __restrict__ P, unsigned short* __restrict__ Q)
{
    __shared__ int hist[512];
    __shared__ int part[256];
    __shared__ unsigned short wlds[8192];
    const int t = threadIdx.x;

    if (blockIdx.x < NBUK) {
        const int k = blockIdx.x;
        const int start = tab[k * BINB];
        const int end = (k == NBUK - 1) ? NE : tab[(k + 1) * BINB];
        hist[t * 2] = 0; hist[t * 2 + 1] = 0;
        __syncthreads();
        for (int e = start + t; e < end; e += 256) atomicAdd(&hist[ebin[e].y & 511], 1);
        __syncthreads();
        const int v0 = hist[t * 2], v1 = hist[t * 2 + 1];
        // zero rows of in-degree-0 nodes (rare); all other rows get fully overwritten
        {
            const uint4 z = make_uint4(0u, 0u, 0u, 0u);
            #pragma unroll
            for (int j = 0; j < 2; ++j) {
                const int node = k * 512 + t * 2 + j;
                const int c = j ? v1 : v0;
                if (node < NN && c == 0) {
                    uint4* r0 = reinterpret_cast<uint4*>(h1r + (long)node * 32);
                    uint4* r1 = reinterpret_cast<uint4*>(xnr + (long)node * 32);
                    #pragma unroll
                    for (int q2 = 0; q2 < 8; ++q2) { r0[q2] = z; r1[q2] = z; }
                }
            }
        }
        part[t] = v0 + v1;
        __syncthreads();
        for (int off = 1; off < 256; off <<= 1) {
            const int u = (t >= off) ? part[t - off] : 0;
            __syncthreads();
            part[t] += u;
            __syncthreads();
        }
        int run = (t == 0) ? 0 : part[t - 1];
        hist[t * 2] = run;
        hist[t * 2 + 1] = run + v0;
        __syncthreads();
        for (int e = start + t; e < end; e += 256) {
            const int2 v = ebin[e];
            const int pos = start + atomicAdd(&hist[v.y & 511], 1);
            sedge[pos] = v;
        }
        return;
    }

    // nodegemm1 blocks
    {
        const uint4* wsrc = reinterpret_cast<const uint4*>(wfrag);
        uint4* wdst = reinterpret_cast<uint4*>(wlds);
        #pragma unroll
        for (int i = 0; i < 4; ++i) wdst[t + i * 256] = wsrc[t + i * 256];
    }
    __syncthreads();
    const int wid = t >> 6, lane = t & 63;
    const int tile = (blockIdx.x - NBUK) * 4 + wid;
    if (tile >= NNTILES) return;
    nodegemm_tile<false>(x, wlds, b1, nullptr, nullptr, P, Q, tile, lane);
}

// ---------------- standalone node GEMM (conv2) ----------------
__global__ __launch_bounds__(256) void nodegemm_kernel(
    const void* __restrict__ xin,
    const unsigned short* __restrict__ wfrag,
    const float* __restrict__ b1,
    const float* __restrict__ scale, const float* __restrict__ shift,
    unsigned short* __restrict__ P, unsigned short* __restrict__ Q)
{
    __shared__ unsigned short wlds[8192];
    {
        const uint4* wsrc = reinterpret_cast<const uint4*>(wfrag);
        uint4* wdst = reinterpret_cast<uint4*>(wlds);
        #pragma unroll
        for (int i = 0; i < 4; ++i) wdst[threadIdx.x + i * 256] = wsrc[threadIdx.x + i * 256];
    }
    __syncthreads();
    const int wid = threadIdx.x >> 6, lane = threadIdx.x & 63;
    const int tile = blockIdx.x * 4 + wid;
    if (tile >= NNTILES) return;
    nodegemm_tile<true>(xin, wlds, b1, scale, shift, P, Q, tile, lane);
}

// ---------------- EdgeConv layer-2: wave = 32 sorted edges ----------------
__global__ __launch_bounds__(256) void edgeconv_kernel(
    const unsigned short* __restrict__ P, const unsigned short* __restrict__ Q,
    const int2* __restrict__ sedge,
    const unsigned short* __restrict__ w2frag,
    const float* __restrict__ b2,
    unsigned* __restrict__ out,              // [NN][32] f16-pair dwords
    int* __restrict__ recd, unsigned* __restrict__ recv)  // recv [NREC][32]
{
    __shared__ unsigned short wlds[4096];
    {
        const uint4* wsrc = reinterpret_cast<const uint4*>(w2frag);
        uint4* wdst = reinterpret_cast<uint4*>(wlds);
        #pragma unroll
        for (int i = 0; i < 2; ++i) wdst[threadIdx.x + i * 256] = wsrc[threadIdx.x + i * 256];
    }
    __syncthreads();

    const int wid  = threadIdx.x >> 6;
    const int lane = threadIdx.x & 63;
    const int hi   = lane >> 5;
    const int ln32 = lane & 31;
    const int tile = xcd_swz(blockIdx.x, gridDim.x) * 4 + wid;  // XCD-chunked for P L2 locality
    if (tile >= NTILES) return;

    const int2 sd = sedge[tile * 32 + ln32];
    const int s = sd.x, d = sd.y;
    const unsigned short* __restrict__ Pr = P + (long)d * 64;
    const unsigned short* __restrict__ Qr = Q + (long)s * 64;

    f32x16 c2a, c2b;
    #pragma unroll
    for (int r = 0; r < 16; ++r) {
        const int row = (r & 3) + 8 * (r >> 2) + 4 * hi;
        c2a[r] = b2[row];
        c2b[r] = b2[32 + row];
    }

    #pragma unroll
    for (int ks = 0; ks < 4; ++ks) {
        const int co = ks * 16 + hi * 8;
        const uint4 pu = *reinterpret_cast<const uint4*>(Pr + co);
        const uint4 qu = *reinterpret_cast<const uint4*>(Qr + co);
        uint4 hh;   // relu(P+Q) in packed f16
        hh.x = pk_max_f16(pk_add_f16(pu.x, qu.x), 0u);
        hh.y = pk_max_f16(pk_add_f16(pu.y, qu.y), 0u);
        hh.z = pk_max_f16(pk_add_f16(pu.z, qu.z), 0u);
        hh.w = pk_max_f16(pk_add_f16(pu.w, qu.w), 0u);
        const f16x8 bfr = __builtin_bit_cast(f16x8, hh);
        const f16x8 a0 = *reinterpret_cast<const f16x8*>(&wlds[(0 * 4 + ks) * 512 + lane * 8]);
        const f16x8 a1 = *reinterpret_cast<const f16x8*>(&wlds[(1 * 4 + ks) * 512 + lane * 8]);
        c2a = __builtin_amdgcn_mfma_f32_32x32x16_f16(a0, bfr, c2a, 0, 0, 0);
        c2b = __builtin_amdgcn_mfma_f32_32x32x16_f16(a1, bfr, c2b, 0, 0, 0);
    }

    // relu + pack to 16 f16-pair dwords
    unsigned pkc[16];
    #pragma unroll
    for (int q = 0; q < 8; ++q) {
        pkc[q]     = pk_max_f16(pkrtz(c2a[2 * q], c2a[2 * q + 1]), 0u);
        pkc[8 + q] = pk_max_f16(pkrtz(c2b[2 * q], c2b[2 * q + 1]), 0u);
    }

    // segmented max over edges within each 32-lane half (keys = d, sorted)
    #pragma unroll
    for (int st = 1; st < 16; st <<= 1) {
        const int dn = __shfl_down(d, st, 32);
        const bool take = (ln32 + st < 32) && (dn == d);
        #pragma unroll
        for (int i = 0; i < 16; ++i) {
            const unsigned o = __shfl_down(pkc[i], st, 32);
            const unsigned m = pk_max_f16(pkc[i], o);
            pkc[i] = take ? m : pkc[i];
        }
    }
    // stage 16 only when some segment spans >16 lanes (~8% of tiles)
    {
        const int dn = __shfl_down(d, 16, 32);
        const bool take = (ln32 + 16 < 32) && (dn == d);
        if (__ballot(take) != 0ull) {
            #pragma unroll
            for (int i = 0; i < 16; ++i) {
                const unsigned o = __shfl_down(pkc[i], 16, 32);
                const unsigned m = pk_max_f16(pkc[i], o);
                pkc[i] = take ? m : pkc[i];
            }
        }
    }
    const int dprev = __shfl_up(d, 1, 32);
    const bool leader = (ln32 == 0) || (d != dprev);
    const unsigned lm = (unsigned)(__ballot(leader) & 0xffffffffull);
    const int L31 = 31 - __builtin_clz(lm);

    if (leader) {
        if (ln32 != 0 && ln32 != L31) {
            unsigned* row = out + (long)d * 32;
            #pragma unroll
            for (int g2 = 0; g2 < 4; ++g2) {
                *reinterpret_cast<uint2*>(row + 4 * g2 + 2 * hi) =
                    make_uint2(pkc[2 * g2], pkc[2 * g2 + 1]);
                *reinterpret_cast<uint2*>(row + 16 + 4 * g2 + 2 * hi) =
                    make_uint2(pkc[8 + 2 * g2], pkc[8 + 2 * g2 + 1]);
            }
        }
        if (ln32 == 0) {
            unsigned* row = recv + (long)(tile * 2) * 32;
            #pragma unroll
            for (int g2 = 0; g2 < 4; ++g2) {
                *reinterpret_cast<uint2*>(row + 4 * g2 + 2 * hi) =
                    make_uint2(pkc[2 * g2], pkc[2 * g2 + 1]);
                *reinterpret_cast<uint2*>(row + 16 + 4 * g2 + 2 * hi) =
                    make_uint2(pkc[8 + 2 * g2], pkc[8 + 2 * g2 + 1]);
            }
            if (hi == 0) recd[tile * 2] = d;
        }
        if (ln32 == L31) {
            unsigned* row = recv + (long)(tile * 2 + 1) * 32;
            #pragma unroll
            for (int g2 = 0; g2 < 4; ++g2) {
                *reinterpret_cast<uint2*>(row + 4 * g2 + 2 * hi) =
                    make_uint2(pkc[2 * g2], pkc[2 * g2 + 1]);
                *reinterpret_cast<uint2*>(row + 16 + 4 * g2 + 2 * hi) =
                    make_uint2(pkc[8 + 2 * g2], pkc[8 + 2 * g2 + 1]);
            }
            if (hi == 0) recd[tile * 2 + 1] = d;
        }
    }
}

// ---------------- fixup: combine boundary records, 2 records per wave -------------
__global__ __launch_bounds__(256) void fixup_kernel(
    const int* __restrict__ recd, const unsigned* __restrict__ recv,
    unsigned* __restrict__ out)
{
    const int wid = threadIdx.x >> 6;
    const int half = (threadIdx.x >> 5) & 1;
    const int c2 = threadIdx.x & 31;
    const int r = blockIdx.x * 8 + wid * 2 + half;
    if (r >= NREC) return;
    const int d = recd[r];
    int lo = r, hi = r;
    while (lo > 0 && recd[lo - 1] == d) --lo;
    while (hi + 1 < NREC && recd[hi + 1] == d) ++hi;
    unsigned m = 0u;   // relu outputs >= 0 -> packed {+0,+0} identity
    for (int rr = lo; rr <= hi; ++rr) m = pk_max_f16(m, recv[(long)rr * 32 + c2]);
    out[(long)d * 32 + c2] = m;
}

// ---------------- BN stats over f16 rows + fused finalize (ticket) ----------------
__global__ __launch_bounds__(256) void stats_kernel(
    const unsigned* __restrict__ h, float* __restrict__ partial,
    const float* __restrict__ g, const float* __restrict__ b,
    float* __restrict__ scale, float* __restrict__ shift, int* __restrict__ ticket)
{
    __shared__ float red[4][256];
    __shared__ float red2[2][256];
    __shared__ int flag;
    const int tid = threadIdx.x;
    const int c2 = tid & 31, r = tid >> 5;   // 8 rows in flight
    float s0 = 0.f, ss0 = 0.f, s1 = 0.f, ss1 = 0.f;
    for (int v = blockIdx.x * 8 + r; v < NN; v += 256 * 8) {
        const unsigned u = h[(long)v * 32 + c2];
        const float a = h2f_lo(u), bb = h2f_hi(u);
        s0 += a; ss0 += a * a; s1 += bb; ss1 += bb * bb;
    }
    red[0][tid] = s0; red[1][tid] = ss0; red[2][tid] = s1; red[3][tid] = ss1;
    __syncthreads();
    if (r == 0) {
        float S0 = 0.f, SS0 = 0.f, S1 = 0.f, SS1 = 0.f;
        #pragma unroll
        for (int q = 0; q < 8; ++q) {
            S0 += red[0][c2 + q * 32]; SS0 += red[1][c2 + q * 32];
            S1 += red[2][c2 + q * 32]; SS1 += red[3][c2 + q * 32];
        }
        partial[blockIdx.x * 128 + 2 * c2]     = S0;
        partial[blockIdx.x * 128 + 2 * c2 + 1] = S1;
        partial[blockIdx.x * 128 + 64 + 2 * c2]     = SS0;
        partial[blockIdx.x * 128 + 64 + 2 * c2 + 1] = SS1;
    }
    __syncthreads();
    if (tid == 0) {
        __threadfence();
        flag = (atomicAdd(ticket, 1) == 255) ? 1 : 0;
    }
    __syncthreads();
    if (!flag) return;
    __threadfence();   // acquire: all blocks' partials visible
    const int c = tid & 63, q = tid >> 6;
    float S = 0.f, SS = 0.f;
    for (int bb2 = q * 64; bb2 < q * 64 + 64; ++bb2) {
        S += partial[bb2 * 128 + c];
        SS += partial[bb2 * 128 + 64 + c];
    }
    red2[0][tid] = S; red2[1][tid] = SS;
    __syncthreads();
    if (q == 0) {
        #pragma unroll
        for (int p = 1; p < 4; ++p) { S += red2[0][c + p * 64]; SS += red2[1][c + p * 64]; }
        const float invN = 1.0f / (float)NN;
        const float mu = S * invN;
        const float var = SS * invN - mu * mu;
        const float sc = g[c] * rsqrtf(var + BN_EPS);
        scale[c] = sc;
        shift[c] = b[c] - mu * sc;
    }
}

// ---------------- node pass: BN2 normalize f16->f32 + segmented pooling -----------
constexpr int NPB = 256;
__global__ __launch_bounds__(256) void nodepass_kernel(
    const unsigned* __restrict__ xnr, float* __restrict__ xn,
    const int* __restrict__ batch,
    const float* __restrict__ scale, const float* __restrict__ shift,
    float* __restrict__ poolsum, unsigned* __restrict__ poolmax, int* __restrict__ counts)
{
    const int base = blockIdx.x * NPB;
    const int r = threadIdx.x >> 5, c2 = threadIdx.x & 31;   // 8 rows x 32 dwords
    const float sc0 = scale[2 * c2], sc1 = scale[2 * c2 + 1];
    const float sh0 = shift[2 * c2], sh1 = shift[2 * c2 + 1];
    int curg = -1; float rs0 = 0.f, rs1 = 0.f, rm0 = -INFINITY, rm1 = -INFINITY; int rc = 0;
    const int vend = (base + NPB < NN) ? base + NPB : NN;
    for (int v = base + r; v < vend; v += 8) {
        const unsigned u = xnr[(long)v * 32 + c2];
        const float v0 = fmaf(h2f_lo(u), sc0, sh0);
        const float v1 = fmaf(h2f_hi(u), sc1, sh1);
        *reinterpret_cast<float2*>(xn + (long)v * 64 + 2 * c2) = make_float2(v0, v1);
        const int g = batch[v];
        if (g != curg) {
            if (curg >= 0) {
                atomicAdd(poolsum + curg * 64 + 2 * c2, rs0);
                atomicAdd(poolsum + curg * 64 + 2 * c2 + 1, rs1);
                atomicMax(poolmax + curg * 64 + 2 * c2, fenc(rm0));
                atomicMax(poolmax + curg * 64 + 2 * c2 + 1, fenc(rm1));
                if (c2 == 0) atomicAdd(counts + curg, rc);
            }
            curg = g; rs0 = rs1 = 0.f; rm0 = rm1 = -INFINITY; rc = 0;
        }
        rs0 += v0; rs1 += v1; rm0 = fmaxf(rm0, v0); rm1 = fmaxf(rm1, v1); ++rc;
    }
    if (curg >= 0) {
        atomicAdd(poolsum + curg * 64 + 2 * c2, rs0);
        atomicAdd(poolsum + curg * 64 + 2 * c2 + 1, rs1);
        atomicMax(poolmax + curg * 64 + 2 * c2, fenc(rm0));
        atomicMax(poolmax + curg * 64 + 2 * c2 + 1, fenc(rm1));
        if (c2 == 0) atomicAdd(counts + curg, rc);
    }
}

// ---------------- final: x_graph + projector MLP + BN + out (1024 thr) ------------
__global__ __launch_bounds__(1024) void final_kernel(
    const float* __restrict__ poolsum, const unsigned* __restrict__ poolmax,
    const int* __restrict__ counts,
    const float* __restrict__ p_w1, const float* __restrict__ p_b1,
    const float* __restrict__ p_bng, const float* __restrict__ p_bnb,
    const float* __restrict__ p_w2, const float* __restrict__ p_b2,
    float* __restrict__ out)
{
    __shared__ float xg[64][128];
    __shared__ float znl[64 * 129];
    __shared__ float red[2][1024];
    __shared__ float scsh[2][128];
    const int tid = threadIdx.x;

    #pragma unroll
    for (int i = 0; i < 8; ++i) {
        const int e2 = tid + i * 1024;
        const int g = e2 >> 7, col = e2 & 127;
        float val;
        if (col < 64) {
            const float cnt = fmaxf((float)counts[g], 1.f);
            val = poolsum[g * 64 + col] / cnt;
        } else {
            const unsigned u = poolmax[g * 64 + col - 64];
            val = (u == 0u) ? 0.f : fdec(u);
        }
        xg[g][col] = val;
        out[OUT_XG + e2] = val;
    }
    __syncthreads();

    const int gg = tid >> 7, t = tid & 127;   // gg in 0..7, 8 graphs each
    float z[8];
    #pragma unroll
    for (int gi = 0; gi < 8; ++gi) z[gi] = p_b1[t];
    for (int j = 0; j < 128; ++j) {
        const float wv = p_w1[j * 128 + t];
        #pragma unroll
        for (int gi = 0; gi < 8; ++gi) z[gi] = fmaf(xg[gg * 8 + gi][j], wv, z[gi]);
    }

    float s = 0.f, ss = 0.f;
    #pragma unroll
    for (int gi = 0; gi < 8; ++gi) { s += z[gi]; ss += z[gi] * z[gi]; }
    red[0][tid] = s; red[1][tid] = ss;
    __syncthreads();
    if (gg == 0) {
        float S = 0.f, SS = 0.f;
        #pragma unroll
        for (int q = 0; q < 8; ++q) { S += red[0][t + q * 128]; SS += red[1][t + q * 128]; }
        const float mu = S / 64.f;
        const float var = SS / 64.f - mu * mu;
        const float sc = p_bng[t] * rsqrtf(var + BN_EPS);
        scsh[0][t] = sc;
        scsh[1][t] = p_bnb[t] - mu * sc;
    }
    __syncthreads();
    const float sc = scsh[0][t], sh = scsh[1][t];
    #pragma unroll
    for (int gi = 0; gi < 8; ++gi) {
        const float zn = fmaxf(fmaf(z[gi], sc, sh), 0.f);
        znl[(gg * 8 + gi) * 129 + t] = zn;
    }
    __syncthreads();

    float zp[8];
    #pragma unroll
    for (int gi = 0; gi < 8; ++gi) zp[gi] = p_b2[t];
    for (int c = 0; c < 128; ++c) {
        const float wv = p_w2[c * 128 + t];
        #pragma unroll
        for (int gi = 0; gi < 8; ++gi) zp[gi] = fmaf(znl[(gg * 8 + gi) * 129 + c], wv, zp[gi]);
    }
    #pragma unroll
    for (int gi = 0; gi < 8; ++gi) out[(gg * 8 + gi) * 128 + t] = zp[gi];
}

// ---------------- launch ----------------
extern "C" void kernel_launch(void* const* d_in, const int* in_sizes, int n_in,
                              void* d_out, int out_size, void* d_ws, size_t ws_size,
                              hipStream_t stream)
{
    const float* x     = (const float*)d_in[0];
    const int*   eidx  = (const int*)d_in[1];
    const int*   batch = (const int*)d_in[2];
    const float* c1w1  = (const float*)d_in[3];
    const float* c1b1  = (const float*)d_in[4];
    const float* c1w2  = (const float*)d_in[5];
    const float* c1b2  = (const float*)d_in[6];
    const float* bn1g  = (const float*)d_in[7];
    const float* bn1b  = (const float*)d_in[8];
    const float* c2w1  = (const float*)d_in[9];
    const float* c2b1  = (const float*)d_in[10];
    const float* c2w2  = (const float*)d_in[11];
    const float* c2b2  = (const float*)d_in[12];
    const float* bn2g  = (const float*)d_in[13];
    const float* bn2b  = (const float*)d_in[14];
    const float* pw1   = (const float*)d_in[15];
    const float* pb1   = (const float*)d_in[16];
    const float* pbng  = (const float*)d_in[17];
    const float* pbnb  = (const float*)d_in[18];
    const float* pw2   = (const float*)d_in[19];
    const float* pb2   = (const float*)d_in[20];

    const int* src = eidx;
    const int* dst = eidx + NE;

    float* ws  = (float*)d_ws;
    float* o   = (float*)d_out;
    unsigned* h1r = (unsigned*)(ws + H1R_OFF);   // f16 rows as dwords
    unsigned* xnr = (unsigned*)(ws + XNR_OFF);
    float* xnode = o + OUT_XNODE;
    int* tick  = (int*)(ws + TICK_OFF);
    int* tab   = (int*)(ws + TAB_OFF);
    int2* ebin  = (int2*)(ws + RECV_OFF);   // staging in RECV region (disjoint lifetime)
    int2* sedge = (int2*)(ws + SEDG_OFF);
    unsigned short* wf1 = (unsigned short*)(ws + WF1_OFF);
    unsigned short* wf2 = (unsigned short*)(ws + WF2_OFF);
    int* recd  = (int*)(ws + RECD_OFF);
    unsigned* recv = (unsigned*)(ws + RECV_OFF);
    unsigned short* Pb = (unsigned short*)(ws + P_OFF);
    unsigned short* Qb = (unsigned short*)(ws + Q_OFF);

    const int convGrid = (NTILES + 3) / 4;
    const int fixGrid  = (NREC + 7) / 8;

    // weight prep + pools/tickets zeroing ∥ bucket histogram (one launch)
    prep_hist_kernel<<<BINB + 129, 256, 0, stream>>>(
        c1w1, c1w2, c2w1, c2w2, wf1, ws + PSUM_OFF, dst, tab);
    // table scan
    scan_tab_kernel<<<1, 1024, 0, stream>>>(tab);
    // clustered scatter into bucket runs
    bin_scatter_kernel<<<BINB, 256, 0, stream>>>(src, dst, tab, ebin);
    // per-bucket counting sort (+ zero empty rows) ∥ nodegemm1 (one launch)
    bucket_ng1_kernel<<<NBUK + NGGRID, 256, 0, stream>>>(
        ebin, tab, sedge, h1r, xnr, x, wf1, c1b1, Pb, Qb);

    // conv1 edge pass -> h1r (f16)
    edgeconv_kernel<<<convGrid, 256, 0, stream>>>(
        Pb, Qb, sedge, wf1 + 8192, c1b2, h1r, recd, recv);
    fixup_kernel<<<fixGrid, 256, 0, stream>>>(recd, recv, h1r);
    // BN1 stats + fused finalize
    stats_kernel<<<256, 256, 0, stream>>>(h1r, ws + PART_OFF, bn1g, bn1b,
                                          ws + SC1_OFF, ws + SH1_OFF, tick + 1);
    // conv2: node GEMM on normalized h1r, edge pass -> xnr
    nodegemm_kernel<<<NGGRID, 256, 0, stream>>>(
        h1r, wf2, c2b1, ws + SC1_OFF, ws + SH1_OFF, Pb, Qb);
    edgeconv_kernel<<<convGrid, 256, 0, stream>>>(
        Pb, Qb, sedge, wf2 + 8192, c2b2, xnr, recd, recv);
    fixup_kernel<<<fixGrid, 256, 0, stream>>>(recd, recv, xnr);
    // BN2 stats + fused finalize
    stats_kernel<<<256, 256, 0, stream>>>(xnr, ws + PART_OFF, bn2g, bn2b,
                                          ws + SC2_OFF, ws + SH2_OFF, tick + 2);
    // normalize xnr -> x_node (f32, d_out) + pooling
    nodepass_kernel<<<(NN + NPB - 1) / NPB, 256, 0, stream>>>(
        xnr, xnode, batch, ws + SC2_OFF, ws + SH2_OFF,
        ws + PSUM_OFF, (unsigned*)(ws + PMAX_OFF), (int*)(ws + CNT_OFF));
    // x_graph + projector
    final_kernel<<<1, 1024, 0, stream>>>(
        ws + PSUM_OFF, (unsigned*)(ws + PMAX_OFF), (int*)(ws + CNT_OFF),
        pw1, pb1, pbng, pbnb, pw2, pb2, o);
}